// Round 8
// baseline (287.088 us; speedup 1.0000x reference)
//
#include <hip/hip_runtime.h>
#include <hip/hip_bf16.h>
#include <cstdint>

// ---------------------------------------------------------------------------
// Attention (B=4, L=2048, C=1024, H=16, D=64). f32 in / f32 out, bf16 MFMA.
//   convert_all -> gemm_qkv (RoPE fused in epilogue; v transposed) ->
//   flash_attn -> gemm_proj
// gemm_qkv: blocks 0-7 emit q, 8-15 k, 16-23 v (which = blockIdx.x>>3,
// uniform). q/k blocks compute C^T via operand-swapped MFMA so each lane
// holds 4 consecutive d for one l -> in-lane RoPE pairs + uint2 stores.
// RoPE applied to fp32 acc pre-quantization; q pre-scaled by 0.125*log2e
// so flash softmax is exp2(q'.k).
// flash_attn v4: 64 q/wave, dbuf K/V, 1 barrier/k-tile, bh-major swizzle.
// MFMA 16x16x32 bf16 layouts (HW-verified): A/B: [lane&15][(lane>>4)*8+j];
// C/D: col=lane&15, row=(lane>>4)*4+reg.
// ---------------------------------------------------------------------------

typedef unsigned short u16;
typedef __attribute__((ext_vector_type(8))) short bf16x8;
typedef __attribute__((ext_vector_type(4))) float f32x4;

#define GLD16(g, l)                                                            \
  __builtin_amdgcn_global_load_lds(                                            \
      (const __attribute__((address_space(1))) void*)(g),                      \
      (__attribute__((address_space(3))) void*)(l), 16, 0, 0)

static __device__ __forceinline__ u16 f32_bf16(float f) {
  union { float f; unsigned u; } v; v.f = f;
  unsigned r = v.u + 0x7FFFu + ((v.u >> 16) & 1u);  // RNE
  return (u16)(r >> 16);
}
static __device__ __forceinline__ float bf16_f32(u16 h) {
  union { unsigned u; float f; } v; v.u = ((unsigned)h) << 16;
  return v.f;
}
static __device__ __forceinline__ unsigned pack_rne(float a, float b) {
  union { float f; unsigned u; } x, y; x.f = a; y.f = b;
  unsigned ua = x.u + 0x7FFFu + ((x.u >> 16) & 1u);
  unsigned ub = y.u + 0x7FFFu + ((y.u >> 16) & 1u);
  return (ua >> 16) | (ub & 0xFFFF0000u);
}
static __device__ __forceinline__ unsigned pack_bf16_hw(float a, float b) {
  float2 t; t.x = a; t.y = b;
  __hip_bfloat162 h = __float22bfloat162_rn(t);
  union { __hip_bfloat162 h; unsigned u; } c; c.h = h;
  return c.u;
}

// ---------------------------------------------------------------------------
// K0: canonicalize ALL inputs to bf16 in one launch; dtype flag read inline
// (cos[0][0]==1.0f: f32 word 0x3F800000, bf16 pair 0x3F803F80).
__global__ __launch_bounds__(256) void convert_all(
    const void* __restrict__ x, const void* __restrict__ wq,
    const void* __restrict__ wp, const void* __restrict__ cs,
    const void* __restrict__ sn, const void* __restrict__ bs,
    u16* __restrict__ xb, u16* __restrict__ wqb, u16* __restrict__ wpb,
    u16* __restrict__ cb, u16* __restrict__ sb, u16* __restrict__ bb) {
  const unsigned f32mode = (((const unsigned*)cs)[0] == 0x3F800000u);
  int blk = blockIdx.x;
  const void* src; u16* dst; int i0, n4;
  if (blk < 8192)       { src = x;  dst = xb;  i0 = blk;         n4 = 2097152; }
  else if (blk < 11264) { src = wq; dst = wqb; i0 = blk - 8192;  n4 = 786432; }
  else if (blk < 12288) { src = wp; dst = wpb; i0 = blk - 11264; n4 = 262144; }
  else if (blk < 12352) { src = cs; dst = cb;  i0 = blk - 12288; n4 = 16384; }
  else if (blk < 12416) { src = sn; dst = sb;  i0 = blk - 12352; n4 = 16384; }
  else                  { src = bs; dst = bb;  i0 = blk - 12416; n4 = 256; }
  int i = i0 * 256 + threadIdx.x;
  if (i >= n4) return;
  if (f32mode) {
    float4 v = ((const float4*)src)[i];
    uint2 o;
    o.x = pack_rne(v.x, v.y);
    o.y = pack_rne(v.z, v.w);
    ((uint2*)dst)[i] = o;
  } else {
    ((uint2*)dst)[i] = ((const uint2*)src)[i];
  }
}

// ---------------------------------------------------------------------------
// Shared GEMM mainloop: 128x128 tile, BK=32, 4 waves 2x2.
// SWAP=false: acc[i][j] = A-rows x B-rows (C layout: col=n of B, row=m of A).
// SWAP=true : operands swapped -> acc holds C^T (col=m of A, row=n of B).
template <bool SWAP>
static __device__ __forceinline__ void gemm_mainloop(
    const u16* __restrict__ A, const u16* __restrict__ Bm, int K,
    int m0, int n0, u16* As, u16* Bs, f32x4 acc[4][4]) {
  const int tid  = threadIdx.x;
  const int lane = tid & 63;
  const int wave = tid >> 6;
  const int n16  = lane & 15;
  const int quad = lane >> 4;
  const int wm = (wave >> 1) * 64;
  const int wn = (wave & 1) * 64;
  const u16* ag = A  + (size_t)(m0 + wave * 16 + (lane >> 2)) * K + (lane & 3) * 8;
  const u16* bg = Bm + (size_t)(n0 + wave * 16 + (lane >> 2)) * K + (lane & 3) * 8;
  u16* al = As + wave * (16 * 32);
  u16* bl = Bs + wave * (16 * 32);
  for (int kt = 0; kt < K; kt += 32) {
    GLD16(ag + kt, al);
    GLD16(ag + (size_t)64 * K + kt, al + 64 * 32);
    GLD16(bg + kt, bl);
    GLD16(bg + (size_t)64 * K + kt, bl + 64 * 32);
    __syncthreads();
    bf16x8 af[4], bf[4];
#pragma unroll
    for (int i = 0; i < 4; i++)
      af[i] = *(const bf16x8*)(As + (wm + i * 16 + n16) * 32 + quad * 8);
#pragma unroll
    for (int j = 0; j < 4; j++)
      bf[j] = *(const bf16x8*)(Bs + (wn + j * 16 + n16) * 32 + quad * 8);
#pragma unroll
    for (int i = 0; i < 4; i++)
#pragma unroll
      for (int j = 0; j < 4; j++)
        acc[i][j] = SWAP
            ? __builtin_amdgcn_mfma_f32_16x16x32_bf16(bf[j], af[i], acc[i][j], 0, 0, 0)
            : __builtin_amdgcn_mfma_f32_16x16x32_bf16(af[i], bf[j], acc[i][j], 0, 0, 0);
    __syncthreads();
  }
}

// ---------------------------------------------------------------------------
// K1: qkv = x @ w_qkv^T with fused RoPE (q,k) and fused transpose (v).
// Blocks 0-7: q (C^T + rope + scale); 8-15: k (C^T + rope); 16-23: v (C,
// transposed [d][l] b64 stores).
__global__ __launch_bounds__(256) void gemm_qkv(
    const u16* __restrict__ x, const u16* __restrict__ w,
    const u16* __restrict__ cosb, const u16* __restrict__ sinb,
    u16* __restrict__ q_ws, u16* __restrict__ k_ws, u16* __restrict__ vt_ws) {
  __shared__ u16 As[128 * 32];
  __shared__ u16 Bs[128 * 32];
  f32x4 acc[4][4];
#pragma unroll
  for (int i = 0; i < 4; i++)
#pragma unroll
    for (int j = 0; j < 4; j++) acc[i][j] = (f32x4){0.f, 0.f, 0.f, 0.f};
  const int m0 = blockIdx.y * 128;
  const int n0 = blockIdx.x * 128;
  const int lane = threadIdx.x & 63, wave = threadIdx.x >> 6;
  const int n16 = lane & 15, quad = lane >> 4;
  const int wm = (wave >> 1) * 64, wn = (wave & 1) * 64;

  if (blockIdx.x < 16) {
    // ---- q/k path: C^T; lane holds l = m0+wm+i*16+n16, f = n0+wn+j*16+quad*4+r
    gemm_mainloop<true>(x, w, 1024, m0, n0, As, Bs, acc);
    const bool isq = (blockIdx.x < 8);
    const float sc = isq ? 0.18033688011112042f : 1.0f;  // 0.125*log2(e) | 1
    u16* const dst = isq ? q_ws : k_ws;
#pragma unroll
    for (int i = 0; i < 4; i++) {
      int lg = m0 + wm + i * 16 + n16;     // global row: b*2048 + l
      int b = lg >> 11, l = lg & 2047;
#pragma unroll
      for (int j = 0; j < 4; j++) {
        int fl = (n0 & 1023) + wn + j * 16 + quad * 4;  // f mod 1024, r=0
        int h = fl >> 6;
        int d0 = fl & 63;                  // even, multiple of 4
        int i0 = d0 >> 1;                  // even -> u32-aligned pair index
        unsigned cw = *(const unsigned*)(cosb + l * 32 + i0);  // cos[i0],cos[i0+1]
        unsigned sw = *(const unsigned*)(sinb + l * 32 + i0);
        float c0 = bf16_f32((u16)(cw & 0xFFFFu)), c1 = bf16_f32((u16)(cw >> 16));
        float s0 = bf16_f32((u16)(sw & 0xFFFFu)), s1 = bf16_f32((u16)(sw >> 16));
        float te0 = acc[i][j][0], to0 = acc[i][j][1];
        float te1 = acc[i][j][2], to1 = acc[i][j][3];
        uint2 o;
        o.x = pack_rne((te0 * c0 - to0 * s0) * sc, (te0 * s0 + to0 * c0) * sc);
        o.y = pack_rne((te1 * c1 - to1 * s1) * sc, (te1 * s1 + to1 * c1) * sc);
        *(uint2*)(dst + (((size_t)b * 16 + h) * 2048 + l) * 64 + d0) = o;
      }
    }
  } else {
    // ---- v path: C; lane holds 4 consecutive l for one d -> [d][l] b64 store
    gemm_mainloop<false>(x, w, 1024, m0, n0, As, Bs, acc);
#pragma unroll
    for (int i = 0; i < 4; i++)
#pragma unroll
      for (int j = 0; j < 4; j++) {
        int f = n0 + wn + j * 16 + n16;
        int rem = f & 1023;
        int h = rem >> 6, d = rem & 63;
        int l0 = m0 + wm + i * 16 + quad * 4;
        int b = l0 >> 11, l = l0 & 2047;
        uint2 o;
        o.x = pack_rne(acc[i][j][0], acc[i][j][1]);
        o.y = pack_rne(acc[i][j][2], acc[i][j][3]);
        size_t idx = (((size_t)b * 16 + h) * 64 + d) * 2048 + l;
        *(uint2*)(vt_ws + idx) = o;
      }
  }
}

// ---------------------------------------------------------------------------
// K4: flash attention v4. 1-D grid 512, bh-major (bh=id&63 -> XCD=bh%8).
// Block = 256 queries, 4 waves x 64 q (4 q-blocks of 16). Double-buffered
// K/V tiles, single barrier per k-tile, prefetch after barrier.
__global__ __launch_bounds__(256, 2) void flash_attn(
    const u16* __restrict__ q_ws, const u16* __restrict__ k_ws,
    const u16* __restrict__ vt_ws, u16* __restrict__ o_ws) {
  __shared__ u16 Ks[2][64 * 64];   // [key][d], 16B chunks XOR-swizzled
  __shared__ u16 Vs[2][64 * 64];   // [d][key], 16B chunks XOR-swizzled
  __shared__ u16 Pa[4 * 64 * 72];  // per-wave P[q(64)][key(64)], stride 72
  const int bh = blockIdx.x & 63;
  const int q0 = (blockIdx.x >> 6) * 256;
  const int b = bh >> 4, h = bh & 15;
  const int tid = threadIdx.x, lane = tid & 63, wave = tid >> 6;
  const int n16 = lane & 15, quad = lane >> 4;
  const int x7 = n16 & 7;
  const size_t hoff = (size_t)bh * (2048 * 64);

  // Q fragments, 4 q-blocks (B-operand: n=q=lane&15, k=d=quad*8+j)
  bf16x8 qf[4][2];
#pragma unroll
  for (int qb = 0; qb < 4; qb++) {
    const u16* qrow = q_ws + hoff + (size_t)(q0 + wave * 64 + qb * 16 + n16) * 64;
    qf[qb][0] = *(const bf16x8*)(qrow + quad * 8);
    qf[qb][1] = *(const bf16x8*)(qrow + 32 + quad * 8);
  }

  f32x4 oacc[4][4];
  f32x4 lq[4];
#pragma unroll
  for (int qb = 0; qb < 4; qb++) {
    lq[qb] = (f32x4){0.f, 0.f, 0.f, 0.f};
#pragma unroll
    for (int s = 0; s < 4; s++) oacc[qb][s] = (f32x4){0.f, 0.f, 0.f, 0.f};
  }

  // staging: lane covers row wave*8+(lane>>3), swizzled chunk (lane&7)^(row&7)
  const int srow = wave * 8 + (lane >> 3);
  const int sw = (lane & 7) ^ ((lane >> 3) & 7);
  const u16* kg = k_ws + hoff + (size_t)srow * 64 + sw * 8;
  const u16* vg = vt_ws + hoff + (size_t)srow * 2048 + sw * 8;
  const int loff = wave * 8 * 64;
  u16* const pw = Pa + wave * (64 * 72);

  // preload tile 0 into buffer 0
  GLD16(kg, &Ks[0][loff]);
  GLD16(kg + 32 * 64, &Ks[0][loff + 32 * 64]);
  GLD16(vg, &Vs[0][loff]);
  GLD16(vg + (size_t)32 * 2048, &Vs[0][loff + 32 * 64]);

  for (int kt = 0; kt < 2048; kt += 64) {
    const int buf = (kt >> 6) & 1;
    __syncthreads();  // drains tile-kt loads (issued a full compute phase ago)
    if (kt + 64 < 2048) {
      const u16* kgn = kg + (size_t)(kt + 64) * 64;
      const u16* vgn = vg + (kt + 64);
      GLD16(kgn, &Ks[buf ^ 1][loff]);
      GLD16(kgn + 32 * 64, &Ks[buf ^ 1][loff + 32 * 64]);
      GLD16(vgn, &Vs[buf ^ 1][loff]);
      GLD16(vgn + (size_t)32 * 2048, &Vs[buf ^ 1][loff + 32 * 64]);
    }
    const u16* ks = Ks[buf];
    const u16* vs = Vs[buf];

    // S^T per key-16-block; K frags shared across all 4 q-blocks.
#pragma unroll
    for (int sub = 0; sub < 4; sub++) {
      const u16* krow = ks + (sub * 16 + n16) * 64;
      bf16x8 kf0 = *(const bf16x8*)(krow + (quad ^ x7) * 8);
      bf16x8 kf1 = *(const bf16x8*)(krow + ((quad + 4) ^ x7) * 8);
#pragma unroll
      for (int qb = 0; qb < 4; qb++) {
        f32x4 z = (f32x4){0.f, 0.f, 0.f, 0.f};
        z = __builtin_amdgcn_mfma_f32_16x16x32_bf16(kf0, qf[qb][0], z, 0, 0, 0);
        z = __builtin_amdgcn_mfma_f32_16x16x32_bf16(kf1, qf[qb][1], z, 0, 0, 0);
        f32x4 p;
#pragma unroll
        for (int r = 0; r < 4; r++) p[r] = __builtin_amdgcn_exp2f(z[r]);  // q pre-scaled
        lq[qb] += p;
        uint2 o;
        o.x = pack_bf16_hw(p[0], p[1]);
        o.y = pack_bf16_hw(p[2], p[3]);
        *(uint2*)(pw + (qb * 16 + n16) * 72 + quad * 4 + sub * 16) = o;
      }
    }

    // PV: P A-frags per q-block; V frags shared across all 4 q-blocks.
    bf16x8 pf[4][2];
#pragma unroll
    for (int qb = 0; qb < 4; qb++) {
      const u16* prow = pw + (qb * 16 + n16) * 72;
      pf[qb][0] = *(const bf16x8*)(prow + quad * 8);
      pf[qb][1] = *(const bf16x8*)(prow + 32 + quad * 8);
    }
#pragma unroll
    for (int sd = 0; sd < 4; sd++) {
      const u16* vrow = vs + (sd * 16 + n16) * 64;
      bf16x8 vf0 = *(const bf16x8*)(vrow + (quad ^ x7) * 8);
      bf16x8 vf1 = *(const bf16x8*)(vrow + ((quad + 4) ^ x7) * 8);
#pragma unroll
      for (int qb = 0; qb < 4; qb++) {
        oacc[qb][sd] = __builtin_amdgcn_mfma_f32_16x16x32_bf16(pf[qb][0], vf0, oacc[qb][sd], 0, 0, 0);
        oacc[qb][sd] = __builtin_amdgcn_mfma_f32_16x16x32_bf16(pf[qb][1], vf1, oacc[qb][sd], 0, 0, 0);
      }
    }
    // no second barrier: next iteration's barrier protects buffer reuse
  }

  // epilogue: per q-block, reduce l over quads, normalize, store bf16 o.
#pragma unroll
  for (int qb = 0; qb < 4; qb++) {
    float l = lq[qb][0] + lq[qb][1] + lq[qb][2] + lq[qb][3];
    l += __shfl_xor(l, 16, 64);
    l += __shfl_xor(l, 32, 64);
    float linv = 1.0f / l;
#pragma unroll
    for (int r = 0; r < 4; r++) {
      float lr = __shfl(linv, quad * 4 + r, 64);
      int row = q0 + wave * 64 + qb * 16 + quad * 4 + r;
      size_t base = ((size_t)b * 2048 + row) * 1024 + h * 64;
#pragma unroll
      for (int sd = 0; sd < 4; sd++)
        o_ws[base + sd * 16 + n16] = f32_bf16(oacc[qb][sd][r] * lr);
    }
  }
}

// ---------------------------------------------------------------------------
// K5: out = o @ w_proj^T + b_proj  -- f32 OUTPUT
__global__ __launch_bounds__(256) void gemm_proj(
    const u16* __restrict__ o, const u16* __restrict__ w,
    const u16* __restrict__ bias, float* __restrict__ out) {
  __shared__ u16 As[128 * 32];
  __shared__ u16 Bs[128 * 32];
  f32x4 acc[4][4];
#pragma unroll
  for (int i = 0; i < 4; i++)
#pragma unroll
    for (int j = 0; j < 4; j++) acc[i][j] = (f32x4){0.f, 0.f, 0.f, 0.f};
  const int m0 = blockIdx.y * 128;
  const int n0 = blockIdx.x * 128;
  gemm_mainloop<false>(o, w, 1024, m0, n0, As, Bs, acc);
  const int lane = threadIdx.x & 63, wave = threadIdx.x >> 6;
  const int n16 = lane & 15, quad = lane >> 4;
  const int wm = (wave >> 1) * 64, wn = (wave & 1) * 64;
#pragma unroll
  for (int i = 0; i < 4; i++)
#pragma unroll
    for (int j = 0; j < 4; j++) {
      int f = n0 + wn + j * 16 + n16;
      float bf = bf16_f32(bias[f]);
#pragma unroll
      for (int r = 0; r < 4; r++) {
        int m = m0 + wm + i * 16 + quad * 4 + r;
        out[(size_t)m * 1024 + f] = acc[i][j][r] + bf;
      }
    }
}

// ---------------------------------------------------------------------------
extern "C" void kernel_launch(void* const* d_in, const int* in_sizes, int n_in,
                              void* d_out, int out_size, void* d_ws, size_t ws_size,
                              hipStream_t stream) {
  float* out = (float*)d_out;

  u16* ws = (u16*)d_ws;
  u16* xb     = ws;                   // 8388608  (dead after gemm_qkv)
  u16* wqkvb  = ws + 8388608;         // 3145728
  u16* wprojb = ws + 11534336;        // 1048576
  u16* cosb   = ws + 12582912;        // 65536
  u16* sinb   = ws + 12648448;        // 65536
  u16* biasb  = ws + 12713984;        // 1024
  u16* qb     = ws + 12715008;        // 8388608  [B][H][L][D]
  u16* kb     = ws + 21103616;        // 8388608  [B][H][L][D]
  u16* vtb    = ws + 29492224;        // 8388608  [B][H][D][L]
  u16* ob     = xb;                   // [B][L][C] overlay (xb dead)

  convert_all<<<12417, 256, 0, stream>>>(
      d_in[0], d_in[3], d_in[4], d_in[1], d_in[2], d_in[5],
      xb, wqkvb, wprojb, cosb, sinb, biasb);

  gemm_qkv<<<dim3(24, 64), 256, 0, stream>>>(xb, wqkvb, cosb, sinb, qb, kb, vtb);
  flash_attn<<<512, 256, 0, stream>>>(qb, kb, vtb, ob);
  gemm_proj<<<dim3(8, 64), 256, 0, stream>>>(ob, wprojb, biasb, out);
}